// Round 1
// baseline (1061.672 us; speedup 1.0000x reference)
//
#include <hip/hip_runtime.h>

#define N_NODES 100000
#define N_EDGES 3200000
#define IN_DIM 500
#define HID 16
#define OUT_DIM 500

// ================= degree / dis =================
__global__ void k_deg(const int* __restrict__ dst, int* __restrict__ cnt, int E) {
    int e = blockIdx.x * blockDim.x + threadIdx.x;
    if (e < E) atomicAdd(&cnt[dst[e]], 1);
}

__global__ void k_dis(const int* __restrict__ cnt, float* __restrict__ dis, int n) {
    int i = blockIdx.x * blockDim.x + threadIdx.x;
    if (i < n) dis[i] = rsqrtf((float)(cnt[i] + 1));  // +1 self-loop
}

// ================= CSR build: scan =================
__global__ __launch_bounds__(1024) void k_scanA(const int* __restrict__ cnt,
                                                int* __restrict__ rowptr,
                                                int* __restrict__ bsum) {
    __shared__ int sh[1024];
    int t = threadIdx.x;
    int i = blockIdx.x * 1024 + t;
    int v = (i < N_NODES) ? cnt[i] : 0;
    sh[t] = v;
    __syncthreads();
    for (int off = 1; off < 1024; off <<= 1) {
        int tmp = (t >= off) ? sh[t - off] : 0;
        __syncthreads();
        sh[t] += tmp;
        __syncthreads();
    }
    if (i < N_NODES) rowptr[i] = sh[t] - v;  // block-local exclusive
    if (t == 1023) bsum[blockIdx.x] = sh[1023];
}

__global__ __launch_bounds__(128) void k_scanB(int* __restrict__ bsum, int nb) {
    __shared__ int sh[128];
    int t = threadIdx.x;
    int v = (t < nb) ? bsum[t] : 0;
    sh[t] = v;
    __syncthreads();
    for (int off = 1; off < 128; off <<= 1) {
        int tmp = (t >= off) ? sh[t - off] : 0;
        __syncthreads();
        sh[t] += tmp;
        __syncthreads();
    }
    if (t < nb) bsum[t] = sh[t] - v;  // exclusive
}

__global__ void k_scanC(int* __restrict__ rowptr, const int* __restrict__ bsum) {
    int i = blockIdx.x * blockDim.x + threadIdx.x;
    if (i < N_NODES) rowptr[i] += bsum[i >> 10];
    if (i == 0) rowptr[N_NODES] = N_EDGES;
}

// ================= CSR fill =================
__global__ void k_fill(const int* __restrict__ src, const int* __restrict__ dst,
                       const int* __restrict__ rowptr, int* __restrict__ cursor,
                       int* __restrict__ csr, int E) {
    int e = blockIdx.x * blockDim.x + threadIdx.x;
    if (e < E) {
        int d = dst[e];
        int p = rowptr[d] + atomicAdd(&cursor[d], 1);
        csr[p] = src[e];
    }
}

// ================= hp[N,16] = dis * (x[N,500] @ W[500,16]) =================
// W transposed in LDS (Wt[j][k]) -> ds_read_b128 instead of 4x ds_read_b32;
// 2 rows per thread amortizes each LDS read across 8 FMAs.
// Bank pattern for Wt row starts: (j*500)%32 = 20j%32 -> 8 distinct banks,
// 2-way aliasing (free per m136); 4 row-groups broadcast the same address.
__global__ __launch_bounds__(256) void k_mm1(const float* __restrict__ x,
                                             const float* __restrict__ W,
                                             const float* __restrict__ dis,
                                             float* __restrict__ hp) {
    __shared__ float Wt[HID * IN_DIM];  // [j][k], 32000 B
    for (int t = threadIdx.x; t < IN_DIM * HID; t += 256) {
        int k = t >> 4;
        int j = t & 15;
        Wt[j * IN_DIM + k] = W[t];
    }
    __syncthreads();
    int g = threadIdx.x >> 4;  // 0..15 row-group
    int j = threadIdx.x & 15;  // feature lane
    int i0 = blockIdx.x * 32 + g;        // rows i0 and i0+16
    int i1 = i0 + 16;
    if (i1 >= N_NODES + 16) return;      // grid exact: 3125*32 = 100000
    const float4* xr0 = (const float4*)(x + (size_t)i0 * IN_DIM);
    const float4* xr1 = (const float4*)(x + (size_t)i1 * IN_DIM);
    const float4* wr = (const float4*)(Wt + j * IN_DIM);
    float acc0 = 0.0f, acc1 = 0.0f;
#pragma unroll 5
    for (int k4 = 0; k4 < IN_DIM / 4; ++k4) {
        float4 w = wr[k4];
        float4 a = xr0[k4];
        float4 c = xr1[k4];
        acc0 += a.x * w.x + a.y * w.y + a.z * w.z + a.w * w.w;
        acc1 += c.x * w.x + c.y * w.y + c.z * w.z + c.w * w.w;
    }
    hp[(size_t)i0 * HID + j] = dis[i0] * acc0;
    hp[(size_t)i1 * HID + j] = dis[i1] * acc1;
}

// ================= hp[N,16] = dis * (o[N,16] @ W[16,16]) =================
__global__ __launch_bounds__(256) void k_mm2(const float* __restrict__ o,
                                             const float* __restrict__ W,
                                             const float* __restrict__ dis,
                                             float* __restrict__ hp) {
    __shared__ float Ws[HID * HID];
    if (threadIdx.x < HID * HID) Ws[threadIdx.x] = W[threadIdx.x];
    __syncthreads();
    int t = blockIdx.x * 256 + threadIdx.x;
    if (t >= N_NODES * HID) return;
    int i = t >> 4;
    int j = t & 15;
    const float* orow = o + (size_t)i * HID;
    float acc = 0.0f;
#pragma unroll
    for (int k = 0; k < HID; ++k) acc += orow[k] * Ws[k * HID + j];
    hp[t] = dis[i] * acc;
}

// ================= hp = dis * o (elementwise, layer-3 pre-agg) =================
__global__ void k_scale(const float* __restrict__ o, const float* __restrict__ dis,
                        float* __restrict__ hp) {
    int t = blockIdx.x * blockDim.x + threadIdx.x;
    if (t < N_NODES * HID) hp[t] = dis[t >> 4] * o[t];
}

// ================= gather: o[d] = [relu](dis[d]*(sum hp[src] + hp[d]) [+ b]) ====
// wave-per-node: 64 lanes = 4 edge-slots x 16 features. Each slot strides the
// edge list by 4 (csr reads: 4 consecutive ints broadcast across 16 lanes;
// hp reads: 4x 64B contiguous segments). Final reduce: 2 shfl_xor stages.
template <int RELU>
__global__ __launch_bounds__(256) void k_gather(const int* __restrict__ rowptr,
                                                const int* __restrict__ csr,
                                                const float* __restrict__ dis,
                                                const float* __restrict__ hp,
                                                const float* __restrict__ b,
                                                float* __restrict__ o) {
    int wave = threadIdx.x >> 6;  // 4 nodes per block
    int lane = threadIdx.x & 63;
    int slot = lane >> 4;         // 0..3 edge slot
    int f = lane & 15;            // feature lane
    int d = blockIdx.x * 4 + wave;
    if (d >= N_NODES) return;
    int start = rowptr[d];
    int end = rowptr[d + 1];
    float s = 0.0f;
    for (int e = start + slot; e < end; e += 4) {
        int sj = csr[e];
        s += hp[(size_t)sj * HID + f];
    }
    s += __shfl_xor(s, 16);
    s += __shfl_xor(s, 32);
    float di = dis[d];
    float v = di * (s + hp[(size_t)d * HID + f]);
    if (RELU) {
        v += b[f];
        v = v > 0.0f ? v : 0.0f;
    }
    if (lane < 16) o[(size_t)d * HID + f] = v;
}

// ================= out[N,500] = a[N,16] @ W[16,500] + b =================
// register-blocked: 4 rows x 4 cols per thread, W in LDS (ds_read_b128)
__global__ __launch_bounds__(256) void k_mm3(const float* __restrict__ a,
                                             const float* __restrict__ W,
                                             const float* __restrict__ b,
                                             float* __restrict__ out) {
    __shared__ float Ws[HID * OUT_DIM];  // 32000 B
    __shared__ float bs[OUT_DIM];
    for (int t = threadIdx.x; t < HID * OUT_DIM; t += 256) Ws[t] = W[t];
    for (int t = threadIdx.x; t < OUT_DIM; t += 256) bs[t] = b[t];
    __syncthreads();
    int ct = threadIdx.x & 127;  // 0..127 (125 active)
    int rt = threadIdx.x >> 7;   // 0..1
    int r0 = blockIdx.x * 8 + rt * 4;
    float areg[4][16];
#pragma unroll
    for (int rr = 0; rr < 4; ++rr) {
        const float4* ap = (const float4*)(a + (size_t)(r0 + rr) * HID);
        float4 v0 = ap[0], v1 = ap[1], v2 = ap[2], v3 = ap[3];
        areg[rr][0] = v0.x;  areg[rr][1] = v0.y;  areg[rr][2] = v0.z;  areg[rr][3] = v0.w;
        areg[rr][4] = v1.x;  areg[rr][5] = v1.y;  areg[rr][6] = v1.z;  areg[rr][7] = v1.w;
        areg[rr][8] = v2.x;  areg[rr][9] = v2.y;  areg[rr][10] = v2.z; areg[rr][11] = v2.w;
        areg[rr][12] = v3.x; areg[rr][13] = v3.y; areg[rr][14] = v3.z; areg[rr][15] = v3.w;
    }
    if (ct >= 125) return;
    int j0 = ct * 4;
    float acc[4][4];
#pragma unroll
    for (int rr = 0; rr < 4; ++rr) {
        acc[rr][0] = bs[j0];
        acc[rr][1] = bs[j0 + 1];
        acc[rr][2] = bs[j0 + 2];
        acc[rr][3] = bs[j0 + 3];
    }
#pragma unroll
    for (int k = 0; k < HID; ++k) {
        float4 w = *(const float4*)&Ws[k * OUT_DIM + j0];
#pragma unroll
        for (int rr = 0; rr < 4; ++rr) {
            acc[rr][0] += areg[rr][k] * w.x;
            acc[rr][1] += areg[rr][k] * w.y;
            acc[rr][2] += areg[rr][k] * w.z;
            acc[rr][3] += areg[rr][k] * w.w;
        }
    }
#pragma unroll
    for (int rr = 0; rr < 4; ++rr) {
        float4 r = make_float4(acc[rr][0], acc[rr][1], acc[rr][2], acc[rr][3]);
        *(float4*)&out[(size_t)(r0 + rr) * OUT_DIM + j0] = r;
    }
}

extern "C" void kernel_launch(void* const* d_in, const int* in_sizes, int n_in,
                              void* d_out, int out_size, void* d_ws, size_t ws_size,
                              hipStream_t stream) {
    const float* x  = (const float*)d_in[0];
    const int* ei   = (const int*)d_in[1];
    const float* W1 = (const float*)d_in[2];
    const float* b1 = (const float*)d_in[3];
    const float* W2 = (const float*)d_in[4];
    const float* b2 = (const float*)d_in[5];
    const float* W3 = (const float*)d_in[6];
    const float* b3 = (const float*)d_in[7];
    float* out = (float*)d_out;

    const int* src = ei;
    const int* dst = ei + N_EDGES;

    // workspace layout (bytes)
    char* w = (char*)d_ws;
    float* dis    = (float*)(w);                 // 100352 f
    int*   cnt    = (int*)(w + 401408);          // 100352 i  (reused as cursor)
    int*   rowptr = (int*)(w + 802816);          // 100608 i
    int*   bsum   = (int*)(w + 1205248);         // 128 i
    int*   csr    = (int*)(w + 1205760);         // 3.2M i
    float* hp     = (float*)(w + 14005760);      // 1.6M f
    float* o      = (float*)(w + 20405760);      // 1.6M f
    // total ~26.81 MB

    const int B = 256;
    int gN   = (N_NODES + B - 1) / B;
    int gE   = (N_EDGES + B - 1) / B;
    int gNH  = (N_NODES * HID + B - 1) / B;   // 6250
    int gG   = (N_NODES + 3) / 4;             // 25000 (wave-per-node)
    int gMM1 = N_NODES / 32;                  // 3125 (exact)
    int gMM3 = N_NODES / 8;                   // 12500 (exact)
    int gScanA = (N_NODES + 1023) / 1024;     // 98

    // ---- degree & dis ----
    hipMemsetAsync(cnt, 0, N_NODES * sizeof(int), stream);
    k_deg<<<gE, B, 0, stream>>>(dst, cnt, N_EDGES);
    k_dis<<<gN, B, 0, stream>>>(cnt, dis, N_NODES);

    // ---- CSR build ----
    k_scanA<<<gScanA, 1024, 0, stream>>>(cnt, rowptr, bsum);
    k_scanB<<<1, 128, 0, stream>>>(bsum, gScanA);
    k_scanC<<<gN, B, 0, stream>>>(rowptr, bsum);
    hipMemsetAsync(cnt, 0, N_NODES * sizeof(int), stream);  // cursor
    k_fill<<<gE, B, 0, stream>>>(src, dst, rowptr, cnt, csr, N_EDGES);

    // ---- layer 1 ----
    k_mm1<<<gMM1, B, 0, stream>>>(x, W1, dis, hp);
    k_gather<1><<<gG, B, 0, stream>>>(rowptr, csr, dis, hp, b1, o);

    // ---- layer 2 ----
    k_mm2<<<gNH, B, 0, stream>>>(o, W2, dis, hp);
    k_gather<1><<<gG, B, 0, stream>>>(rowptr, csr, dis, hp, b2, o);

    // ---- layer 3: aggregate at 16 dims, then W3 ----
    k_scale<<<gNH, B, 0, stream>>>(o, dis, hp);
    k_gather<0><<<gG, B, 0, stream>>>(rowptr, csr, dis, hp, b3, o);
    k_mm3<<<gMM3, B, 0, stream>>>(o, W3, b3, out);
}

// Round 2
// 986.556 us; speedup vs baseline: 1.0761x; 1.0761x over previous
//
#include <hip/hip_runtime.h>

#define N_NODES 100000
#define N_EDGES 3200000
#define IN_DIM 500
#define HID 16
#define OUT_DIM 500

// ================= degree / dis =================
__global__ void k_deg(const int* __restrict__ dst, int* __restrict__ cnt, int E) {
    int e = blockIdx.x * blockDim.x + threadIdx.x;
    if (e < E) atomicAdd(&cnt[dst[e]], 1);
}

__global__ void k_dis(const int* __restrict__ cnt, float* __restrict__ dis, int n) {
    int i = blockIdx.x * blockDim.x + threadIdx.x;
    if (i < n) dis[i] = rsqrtf((float)(cnt[i] + 1));  // +1 self-loop
}

// ================= CSR build: scan =================
__global__ __launch_bounds__(1024) void k_scanA(const int* __restrict__ cnt,
                                                int* __restrict__ rowptr,
                                                int* __restrict__ bsum) {
    __shared__ int sh[1024];
    int t = threadIdx.x;
    int i = blockIdx.x * 1024 + t;
    int v = (i < N_NODES) ? cnt[i] : 0;
    sh[t] = v;
    __syncthreads();
    for (int off = 1; off < 1024; off <<= 1) {
        int tmp = (t >= off) ? sh[t - off] : 0;
        __syncthreads();
        sh[t] += tmp;
        __syncthreads();
    }
    if (i < N_NODES) rowptr[i] = sh[t] - v;  // block-local exclusive
    if (t == 1023) bsum[blockIdx.x] = sh[1023];
}

__global__ __launch_bounds__(128) void k_scanB(int* __restrict__ bsum, int nb) {
    __shared__ int sh[128];
    int t = threadIdx.x;
    int v = (t < nb) ? bsum[t] : 0;
    sh[t] = v;
    __syncthreads();
    for (int off = 1; off < 128; off <<= 1) {
        int tmp = (t >= off) ? sh[t - off] : 0;
        __syncthreads();
        sh[t] += tmp;
        __syncthreads();
    }
    if (t < nb) bsum[t] = sh[t] - v;  // exclusive
}

__global__ void k_scanC(int* __restrict__ rowptr, const int* __restrict__ bsum) {
    int i = blockIdx.x * blockDim.x + threadIdx.x;
    if (i < N_NODES) rowptr[i] += bsum[i >> 10];
    if (i == 0) rowptr[N_NODES] = N_EDGES;
}

// ================= CSR fill =================
__global__ void k_fill(const int* __restrict__ src, const int* __restrict__ dst,
                       const int* __restrict__ rowptr, int* __restrict__ cursor,
                       int* __restrict__ csr, int E) {
    int e = blockIdx.x * blockDim.x + threadIdx.x;
    if (e < E) {
        int d = dst[e];
        int p = rowptr[d] + atomicAdd(&cursor[d], 1);
        csr[p] = src[e];
    }
}

// ================= hp[N,16] = dis * (x[N,500] @ W[500,16]) =================
// row-per-lane: each lane owns one x row (zero VMEM redundancy, full distinct
// data per load instruction). W indices depend only on the uniform k4 loop
// counter -> compiler emits s_load; FMAs are v_fmac vacc, s_w, v_a (scalar
// pipe carries all weight traffic; no LDS at all).
__global__ __launch_bounds__(256) void k_mm1(const float* __restrict__ x,
                                             const float* __restrict__ W,
                                             const float* __restrict__ dis,
                                             float* __restrict__ hp) {
    int row = blockIdx.x * 256 + threadIdx.x;
    if (row >= N_NODES) return;
    const float4* xr = (const float4*)(x + (size_t)row * IN_DIM);
    float acc[HID];
#pragma unroll
    for (int j = 0; j < HID; ++j) acc[j] = 0.0f;
    for (int k4 = 0; k4 < IN_DIM / 4; ++k4) {
        float4 a = xr[k4];
        const float* Wk = W + (size_t)(4 * k4) * HID;  // uniform address
#pragma unroll
        for (int j = 0; j < HID; ++j) {
            acc[j] += a.x * Wk[j] + a.y * Wk[HID + j] +
                      a.z * Wk[2 * HID + j] + a.w * Wk[3 * HID + j];
        }
    }
    float di = dis[row];
    float4* hr = (float4*)(hp + (size_t)row * HID);
#pragma unroll
    for (int q = 0; q < 4; ++q)
        hr[q] = make_float4(di * acc[4 * q + 0], di * acc[4 * q + 1],
                            di * acc[4 * q + 2], di * acc[4 * q + 3]);
}

// ================= hp[N,16] = dis * (o[N,16] @ W[16,16]) =================
// same row-per-lane + scalar-W pattern (W2 = 1 KB, L2-hot)
__global__ __launch_bounds__(256) void k_mm2(const float* __restrict__ o,
                                             const float* __restrict__ W,
                                             const float* __restrict__ dis,
                                             float* __restrict__ hp) {
    int row = blockIdx.x * 256 + threadIdx.x;
    if (row >= N_NODES) return;
    const float4* orow = (const float4*)(o + (size_t)row * HID);
    float av[HID];
#pragma unroll
    for (int q = 0; q < 4; ++q) {
        float4 a = orow[q];
        av[4 * q + 0] = a.x; av[4 * q + 1] = a.y;
        av[4 * q + 2] = a.z; av[4 * q + 3] = a.w;
    }
    float acc[HID];
#pragma unroll
    for (int j = 0; j < HID; ++j) acc[j] = 0.0f;
#pragma unroll
    for (int k = 0; k < HID; ++k) {
#pragma unroll
        for (int j = 0; j < HID; ++j) acc[j] += av[k] * W[k * HID + j];
    }
    float di = dis[row];
    float4* hr = (float4*)(hp + (size_t)row * HID);
#pragma unroll
    for (int q = 0; q < 4; ++q)
        hr[q] = make_float4(di * acc[4 * q + 0], di * acc[4 * q + 1],
                            di * acc[4 * q + 2], di * acc[4 * q + 3]);
}

// ================= hp = dis * o (elementwise, layer-3 pre-agg) =================
__global__ void k_scale(const float* __restrict__ o, const float* __restrict__ dis,
                        float* __restrict__ hp) {
    int t = blockIdx.x * blockDim.x + threadIdx.x;
    if (t < N_NODES * HID) hp[t] = dis[t >> 4] * o[t];
}

// ================= gather: o[d] = [relu](dis[d]*(sum hp[src] + hp[d]) [+ b]) ====
// (baseline version from the 991us run — 16 node-groups/block, shfl broadcast)
template <int RELU>
__global__ __launch_bounds__(256) void k_gather(const int* __restrict__ rowptr,
                                                const int* __restrict__ csr,
                                                const float* __restrict__ dis,
                                                const float* __restrict__ hp,
                                                const float* __restrict__ b,
                                                float* __restrict__ o) {
    int g = threadIdx.x >> 4;   // 16 node-groups per block
    int f = threadIdx.x & 15;   // feature lane
    int d = blockIdx.x * 16 + g;
    int start = rowptr[d];
    int end = rowptr[d + 1];
    float s = 0.0f;
    for (int e0 = start; e0 < end; e0 += 16) {
        int idx = e0 + f;
        int sid = (idx < end) ? csr[idx] : 0;
        int m = end - e0;
        if (m > 16) m = 16;
        for (int j = 0; j < m; ++j) {
            int sj = __shfl(sid, j, 16);  // uniform within the 16-lane group
            s += hp[(size_t)sj * HID + f];
        }
    }
    float di = dis[d];
    float v = di * (s + hp[(size_t)d * HID + f]);
    if (RELU) {
        v += b[f];
        v = v > 0.0f ? v : 0.0f;
    }
    o[(size_t)d * HID + f] = v;
}

// ================= out[N,500] = a[N,16] @ W[16,500] + b =================
// register-blocked: 4 rows x 4 cols per thread, W in LDS (ds_read_b128)
__global__ __launch_bounds__(256) void k_mm3(const float* __restrict__ a,
                                             const float* __restrict__ W,
                                             const float* __restrict__ b,
                                             float* __restrict__ out) {
    __shared__ float Ws[HID * OUT_DIM];  // 32000 B
    __shared__ float bs[OUT_DIM];
    for (int t = threadIdx.x; t < HID * OUT_DIM; t += 256) Ws[t] = W[t];
    for (int t = threadIdx.x; t < OUT_DIM; t += 256) bs[t] = b[t];
    __syncthreads();
    int ct = threadIdx.x & 127;  // 0..127 (125 active)
    int rt = threadIdx.x >> 7;   // 0..1
    int r0 = blockIdx.x * 8 + rt * 4;
    float areg[4][16];
#pragma unroll
    for (int rr = 0; rr < 4; ++rr) {
        const float4* ap = (const float4*)(a + (size_t)(r0 + rr) * HID);
        float4 v0 = ap[0], v1 = ap[1], v2 = ap[2], v3 = ap[3];
        areg[rr][0] = v0.x;  areg[rr][1] = v0.y;  areg[rr][2] = v0.z;  areg[rr][3] = v0.w;
        areg[rr][4] = v1.x;  areg[rr][5] = v1.y;  areg[rr][6] = v1.z;  areg[rr][7] = v1.w;
        areg[rr][8] = v2.x;  areg[rr][9] = v2.y;  areg[rr][10] = v2.z; areg[rr][11] = v2.w;
        areg[rr][12] = v3.x; areg[rr][13] = v3.y; areg[rr][14] = v3.z; areg[rr][15] = v3.w;
    }
    if (ct >= 125) return;
    int j0 = ct * 4;
    float acc[4][4];
#pragma unroll
    for (int rr = 0; rr < 4; ++rr) {
        acc[rr][0] = bs[j0];
        acc[rr][1] = bs[j0 + 1];
        acc[rr][2] = bs[j0 + 2];
        acc[rr][3] = bs[j0 + 3];
    }
#pragma unroll
    for (int k = 0; k < HID; ++k) {
        float4 w = *(const float4*)&Ws[k * OUT_DIM + j0];
#pragma unroll
        for (int rr = 0; rr < 4; ++rr) {
            acc[rr][0] += areg[rr][k] * w.x;
            acc[rr][1] += areg[rr][k] * w.y;
            acc[rr][2] += areg[rr][k] * w.z;
            acc[rr][3] += areg[rr][k] * w.w;
        }
    }
#pragma unroll
    for (int rr = 0; rr < 4; ++rr) {
        float4 r = make_float4(acc[rr][0], acc[rr][1], acc[rr][2], acc[rr][3]);
        *(float4*)&out[(size_t)(r0 + rr) * OUT_DIM + j0] = r;
    }
}

extern "C" void kernel_launch(void* const* d_in, const int* in_sizes, int n_in,
                              void* d_out, int out_size, void* d_ws, size_t ws_size,
                              hipStream_t stream) {
    const float* x  = (const float*)d_in[0];
    const int* ei   = (const int*)d_in[1];
    const float* W1 = (const float*)d_in[2];
    const float* b1 = (const float*)d_in[3];
    const float* W2 = (const float*)d_in[4];
    const float* b2 = (const float*)d_in[5];
    const float* W3 = (const float*)d_in[6];
    const float* b3 = (const float*)d_in[7];
    float* out = (float*)d_out;

    const int* src = ei;
    const int* dst = ei + N_EDGES;

    // workspace layout (bytes)
    char* w = (char*)d_ws;
    float* dis    = (float*)(w);                 // 100352 f
    int*   cnt    = (int*)(w + 401408);          // 100352 i  (reused as cursor)
    int*   rowptr = (int*)(w + 802816);          // 100608 i
    int*   bsum   = (int*)(w + 1205248);         // 128 i
    int*   csr    = (int*)(w + 1205760);         // 3.2M i
    float* hp     = (float*)(w + 14005760);      // 1.6M f
    float* o      = (float*)(w + 20405760);      // 1.6M f
    // total ~26.81 MB

    const int B = 256;
    int gN   = (N_NODES + B - 1) / B;         // 391
    int gE   = (N_EDGES + B - 1) / B;
    int gNH  = (N_NODES * HID + B - 1) / B;   // 6250
    int gG   = N_NODES / 16;                  // 6250 (exact)
    int gMM3 = N_NODES / 8;                   // 12500 (exact)
    int gScanA = (N_NODES + 1023) / 1024;     // 98

    // ---- degree & dis ----
    hipMemsetAsync(cnt, 0, N_NODES * sizeof(int), stream);
    k_deg<<<gE, B, 0, stream>>>(dst, cnt, N_EDGES);
    k_dis<<<gN, B, 0, stream>>>(cnt, dis, N_NODES);

    // ---- CSR build ----
    k_scanA<<<gScanA, 1024, 0, stream>>>(cnt, rowptr, bsum);
    k_scanB<<<1, 128, 0, stream>>>(bsum, gScanA);
    k_scanC<<<gN, B, 0, stream>>>(rowptr, bsum);
    hipMemsetAsync(cnt, 0, N_NODES * sizeof(int), stream);  // cursor
    k_fill<<<gE, B, 0, stream>>>(src, dst, rowptr, cnt, csr, N_EDGES);

    // ---- layer 1 ----
    k_mm1<<<gN, B, 0, stream>>>(x, W1, dis, hp);
    k_gather<1><<<gG, B, 0, stream>>>(rowptr, csr, dis, hp, b1, o);

    // ---- layer 2 ----
    k_mm2<<<gN, B, 0, stream>>>(o, W2, dis, hp);
    k_gather<1><<<gG, B, 0, stream>>>(rowptr, csr, dis, hp, b2, o);

    // ---- layer 3: aggregate at 16 dims, then W3 ----
    k_scale<<<gNH, B, 0, stream>>>(o, dis, hp);
    k_gather<0><<<gG, B, 0, stream>>>(rowptr, csr, dis, hp, b3, o);
    k_mm3<<<gMM3, B, 0, stream>>>(o, W3, b3, out);
}

// Round 3
// 937.231 us; speedup vs baseline: 1.1328x; 1.0526x over previous
//
#include <hip/hip_runtime.h>

#define N_NODES 100000
#define N_EDGES 3200000
#define IN_DIM 500
#define HID 16
#define OUT_DIM 500

// ================= degree / dis =================
__global__ void k_deg(const int* __restrict__ dst, int* __restrict__ cnt, int E) {
    int e = blockIdx.x * blockDim.x + threadIdx.x;
    if (e < E) atomicAdd(&cnt[dst[e]], 1);
}

__global__ void k_dis(const int* __restrict__ cnt, float* __restrict__ dis, int n) {
    int i = blockIdx.x * blockDim.x + threadIdx.x;
    if (i < n) dis[i] = rsqrtf((float)(cnt[i] + 1));  // +1 self-loop
}

// ================= CSR build: scan =================
__global__ __launch_bounds__(1024) void k_scanA(const int* __restrict__ cnt,
                                                int* __restrict__ rowptr,
                                                int* __restrict__ bsum) {
    __shared__ int sh[1024];
    int t = threadIdx.x;
    int i = blockIdx.x * 1024 + t;
    int v = (i < N_NODES) ? cnt[i] : 0;
    sh[t] = v;
    __syncthreads();
    for (int off = 1; off < 1024; off <<= 1) {
        int tmp = (t >= off) ? sh[t - off] : 0;
        __syncthreads();
        sh[t] += tmp;
        __syncthreads();
    }
    if (i < N_NODES) rowptr[i] = sh[t] - v;  // block-local exclusive
    if (t == 1023) bsum[blockIdx.x] = sh[1023];
}

__global__ __launch_bounds__(128) void k_scanB(int* __restrict__ bsum, int nb) {
    __shared__ int sh[128];
    int t = threadIdx.x;
    int v = (t < nb) ? bsum[t] : 0;
    sh[t] = v;
    __syncthreads();
    for (int off = 1; off < 128; off <<= 1) {
        int tmp = (t >= off) ? sh[t - off] : 0;
        __syncthreads();
        sh[t] += tmp;
        __syncthreads();
    }
    if (t < nb) bsum[t] = sh[t] - v;  // exclusive
}

__global__ void k_scanC(int* __restrict__ rowptr, const int* __restrict__ bsum) {
    int i = blockIdx.x * blockDim.x + threadIdx.x;
    if (i < N_NODES) rowptr[i] += bsum[i >> 10];
    if (i == 0) rowptr[N_NODES] = N_EDGES;
}

// ================= CSR fill =================
__global__ void k_fill(const int* __restrict__ src, const int* __restrict__ dst,
                       const int* __restrict__ rowptr, int* __restrict__ cursor,
                       int* __restrict__ csr, int E) {
    int e = blockIdx.x * blockDim.x + threadIdx.x;
    if (e < E) {
        int d = dst[e];
        int p = rowptr[d] + atomicAdd(&cursor[d], 1);
        csr[p] = src[e];
    }
}

// ================= hp[N,16] = dis * (x[N,500] @ W[500,16]) =================
// row-per-lane + scalar-pipe W (verified R2: VGPR 24, no LDS) + manual 2-stage
// software pipeline over 8-float4 (128B) groups. R2 showed the limiter was
// serialized load latency (1 float4 in flight, VALUBusy 7.8%); ping-pong
// register buffers keep 8 loads in flight while FMAs run on the other buffer.
__global__ __launch_bounds__(256) void k_mm1(const float* __restrict__ x,
                                             const float* __restrict__ W,
                                             const float* __restrict__ dis,
                                             float* __restrict__ hp) {
    int row = blockIdx.x * 256 + threadIdx.x;
    if (row >= N_NODES) return;
    const float4* xr = (const float4*)(x + (size_t)row * IN_DIM);
    float acc[HID];
#pragma unroll
    for (int j = 0; j < HID; ++j) acc[j] = 0.0f;

    float4 A[8], B[8];
#pragma unroll
    for (int m = 0; m < 8; ++m) A[m] = xr[m];

    // 512 FMAs on one 8-float4 group; W address uniform -> scalar pipe
#define MM1_GROUP(buf, g)                                                 \
    {                                                                     \
        const float* Wg = W + (size_t)(g) * 32 * HID;                     \
        _Pragma("unroll") for (int m = 0; m < 8; ++m) {                   \
            float4 a = buf[m];                                            \
            _Pragma("unroll") for (int j = 0; j < HID; ++j) {             \
                acc[j] += a.x * Wg[(4 * m + 0) * HID + j]                 \
                        + a.y * Wg[(4 * m + 1) * HID + j]                 \
                        + a.z * Wg[(4 * m + 2) * HID + j]                 \
                        + a.w * Wg[(4 * m + 3) * HID + j];                \
            }                                                             \
        }                                                                 \
    }

    // 15 full groups (float4 0..119), pipelined two at a time
    for (int gg = 0; gg < 7; ++gg) {
        int g0 = 2 * gg;
#pragma unroll
        for (int m = 0; m < 8; ++m) B[m] = xr[8 * (g0 + 1) + m];
        MM1_GROUP(A, g0);
#pragma unroll
        for (int m = 0; m < 8; ++m) A[m] = xr[8 * (g0 + 2) + m];
        MM1_GROUP(B, g0 + 1);
    }
    MM1_GROUP(A, 14);
    // tail: float4 indices 120..124 (k = 480..499)
#pragma unroll
    for (int m = 0; m < 5; ++m) {
        float4 a = xr[120 + m];
        const float* Wg = W + (size_t)(480 + 4 * m) * HID;
#pragma unroll
        for (int j = 0; j < HID; ++j) {
            acc[j] += a.x * Wg[j] + a.y * Wg[HID + j] +
                      a.z * Wg[2 * HID + j] + a.w * Wg[3 * HID + j];
        }
    }
#undef MM1_GROUP

    float di = dis[row];
    float4* hr = (float4*)(hp + (size_t)row * HID);
#pragma unroll
    for (int q = 0; q < 4; ++q)
        hr[q] = make_float4(di * acc[4 * q + 0], di * acc[4 * q + 1],
                            di * acc[4 * q + 2], di * acc[4 * q + 3]);
}

// ================= hp[N,16] = dis * (o[N,16] @ W[16,16]) =================
// same row-per-lane + scalar-W pattern (W2 = 1 KB, L2-hot)
__global__ __launch_bounds__(256) void k_mm2(const float* __restrict__ o,
                                             const float* __restrict__ W,
                                             const float* __restrict__ dis,
                                             float* __restrict__ hp) {
    int row = blockIdx.x * 256 + threadIdx.x;
    if (row >= N_NODES) return;
    const float4* orow = (const float4*)(o + (size_t)row * HID);
    float av[HID];
#pragma unroll
    for (int q = 0; q < 4; ++q) {
        float4 a = orow[q];
        av[4 * q + 0] = a.x; av[4 * q + 1] = a.y;
        av[4 * q + 2] = a.z; av[4 * q + 3] = a.w;
    }
    float acc[HID];
#pragma unroll
    for (int j = 0; j < HID; ++j) acc[j] = 0.0f;
#pragma unroll
    for (int k = 0; k < HID; ++k) {
#pragma unroll
        for (int j = 0; j < HID; ++j) acc[j] += av[k] * W[k * HID + j];
    }
    float di = dis[row];
    float4* hr = (float4*)(hp + (size_t)row * HID);
#pragma unroll
    for (int q = 0; q < 4; ++q)
        hr[q] = make_float4(di * acc[4 * q + 0], di * acc[4 * q + 1],
                            di * acc[4 * q + 2], di * acc[4 * q + 3]);
}

// ================= hp = dis * o (elementwise, layer-3 pre-agg) =================
__global__ void k_scale(const float* __restrict__ o, const float* __restrict__ dis,
                        float* __restrict__ hp) {
    int t = blockIdx.x * blockDim.x + threadIdx.x;
    if (t < N_NODES * HID) hp[t] = dis[t >> 4] * o[t];
}

// ================= gather: o[d] = [relu](dis[d]*(sum hp[src] + hp[d]) [+ b]) ====
// (baseline version from the 991us run — 16 node-groups/block, shfl broadcast)
template <int RELU>
__global__ __launch_bounds__(256) void k_gather(const int* __restrict__ rowptr,
                                                const int* __restrict__ csr,
                                                const float* __restrict__ dis,
                                                const float* __restrict__ hp,
                                                const float* __restrict__ b,
                                                float* __restrict__ o) {
    int g = threadIdx.x >> 4;   // 16 node-groups per block
    int f = threadIdx.x & 15;   // feature lane
    int d = blockIdx.x * 16 + g;
    int start = rowptr[d];
    int end = rowptr[d + 1];
    float s = 0.0f;
    for (int e0 = start; e0 < end; e0 += 16) {
        int idx = e0 + f;
        int sid = (idx < end) ? csr[idx] : 0;
        int m = end - e0;
        if (m > 16) m = 16;
        for (int j = 0; j < m; ++j) {
            int sj = __shfl(sid, j, 16);  // uniform within the 16-lane group
            s += hp[(size_t)sj * HID + f];
        }
    }
    float di = dis[d];
    float v = di * (s + hp[(size_t)d * HID + f]);
    if (RELU) {
        v += b[f];
        v = v > 0.0f ? v : 0.0f;
    }
    o[(size_t)d * HID + f] = v;
}

// ================= out[N,500] = a[N,16] @ W[16,500] + b =================
// register-blocked: 4 rows x 4 cols per thread, W in LDS (ds_read_b128)
__global__ __launch_bounds__(256) void k_mm3(const float* __restrict__ a,
                                             const float* __restrict__ W,
                                             const float* __restrict__ b,
                                             float* __restrict__ out) {
    __shared__ float Ws[HID * OUT_DIM];  // 32000 B
    __shared__ float bs[OUT_DIM];
    for (int t = threadIdx.x; t < HID * OUT_DIM; t += 256) Ws[t] = W[t];
    for (int t = threadIdx.x; t < OUT_DIM; t += 256) bs[t] = b[t];
    __syncthreads();
    int ct = threadIdx.x & 127;  // 0..127 (125 active)
    int rt = threadIdx.x >> 7;   // 0..1
    int r0 = blockIdx.x * 8 + rt * 4;
    float areg[4][16];
#pragma unroll
    for (int rr = 0; rr < 4; ++rr) {
        const float4* ap = (const float4*)(a + (size_t)(r0 + rr) * HID);
        float4 v0 = ap[0], v1 = ap[1], v2 = ap[2], v3 = ap[3];
        areg[rr][0] = v0.x;  areg[rr][1] = v0.y;  areg[rr][2] = v0.z;  areg[rr][3] = v0.w;
        areg[rr][4] = v1.x;  areg[rr][5] = v1.y;  areg[rr][6] = v1.z;  areg[rr][7] = v1.w;
        areg[rr][8] = v2.x;  areg[rr][9] = v2.y;  areg[rr][10] = v2.z; areg[rr][11] = v2.w;
        areg[rr][12] = v3.x; areg[rr][13] = v3.y; areg[rr][14] = v3.z; areg[rr][15] = v3.w;
    }
    if (ct >= 125) return;
    int j0 = ct * 4;
    float acc[4][4];
#pragma unroll
    for (int rr = 0; rr < 4; ++rr) {
        acc[rr][0] = bs[j0];
        acc[rr][1] = bs[j0 + 1];
        acc[rr][2] = bs[j0 + 2];
        acc[rr][3] = bs[j0 + 3];
    }
#pragma unroll
    for (int k = 0; k < HID; ++k) {
        float4 w = *(const float4*)&Ws[k * OUT_DIM + j0];
#pragma unroll
        for (int rr = 0; rr < 4; ++rr) {
            acc[rr][0] += areg[rr][k] * w.x;
            acc[rr][1] += areg[rr][k] * w.y;
            acc[rr][2] += areg[rr][k] * w.z;
            acc[rr][3] += areg[rr][k] * w.w;
        }
    }
#pragma unroll
    for (int rr = 0; rr < 4; ++rr) {
        float4 r = make_float4(acc[rr][0], acc[rr][1], acc[rr][2], acc[rr][3]);
        *(float4*)&out[(size_t)(r0 + rr) * OUT_DIM + j0] = r;
    }
}

extern "C" void kernel_launch(void* const* d_in, const int* in_sizes, int n_in,
                              void* d_out, int out_size, void* d_ws, size_t ws_size,
                              hipStream_t stream) {
    const float* x  = (const float*)d_in[0];
    const int* ei   = (const int*)d_in[1];
    const float* W1 = (const float*)d_in[2];
    const float* b1 = (const float*)d_in[3];
    const float* W2 = (const float*)d_in[4];
    const float* b2 = (const float*)d_in[5];
    const float* W3 = (const float*)d_in[6];
    const float* b3 = (const float*)d_in[7];
    float* out = (float*)d_out;

    const int* src = ei;
    const int* dst = ei + N_EDGES;

    // workspace layout (bytes)
    char* w = (char*)d_ws;
    float* dis    = (float*)(w);                 // 100352 f
    int*   cnt    = (int*)(w + 401408);          // 100352 i  (reused as cursor)
    int*   rowptr = (int*)(w + 802816);          // 100608 i
    int*   bsum   = (int*)(w + 1205248);         // 128 i
    int*   csr    = (int*)(w + 1205760);         // 3.2M i
    float* hp     = (float*)(w + 14005760);      // 1.6M f
    float* o      = (float*)(w + 20405760);      // 1.6M f
    // total ~26.81 MB

    const int B = 256;
    int gN   = (N_NODES + B - 1) / B;         // 391
    int gE   = (N_EDGES + B - 1) / B;
    int gNH  = (N_NODES * HID + B - 1) / B;   // 6250
    int gG   = N_NODES / 16;                  // 6250 (exact)
    int gMM3 = N_NODES / 8;                   // 12500 (exact)
    int gScanA = (N_NODES + 1023) / 1024;     // 98

    // ---- degree & dis ----
    hipMemsetAsync(cnt, 0, N_NODES * sizeof(int), stream);
    k_deg<<<gE, B, 0, stream>>>(dst, cnt, N_EDGES);
    k_dis<<<gN, B, 0, stream>>>(cnt, dis, N_NODES);

    // ---- CSR build ----
    k_scanA<<<gScanA, 1024, 0, stream>>>(cnt, rowptr, bsum);
    k_scanB<<<1, 128, 0, stream>>>(bsum, gScanA);
    k_scanC<<<gN, B, 0, stream>>>(rowptr, bsum);
    hipMemsetAsync(cnt, 0, N_NODES * sizeof(int), stream);  // cursor
    k_fill<<<gE, B, 0, stream>>>(src, dst, rowptr, cnt, csr, N_EDGES);

    // ---- layer 1 ----
    k_mm1<<<gN, B, 0, stream>>>(x, W1, dis, hp);
    k_gather<1><<<gG, B, 0, stream>>>(rowptr, csr, dis, hp, b1, o);

    // ---- layer 2 ----
    k_mm2<<<gN, B, 0, stream>>>(o, W2, dis, hp);
    k_gather<1><<<gG, B, 0, stream>>>(rowptr, csr, dis, hp, b2, o);

    // ---- layer 3: aggregate at 16 dims, then W3 ----
    k_scale<<<gNH, B, 0, stream>>>(o, dis, hp);
    k_gather<0><<<gG, B, 0, stream>>>(rowptr, csr, dis, hp, b3, o);
    k_mm3<<<gMM3, B, 0, stream>>>(o, W3, b3, out);
}

// Round 4
// 825.307 us; speedup vs baseline: 1.2864x; 1.1356x over previous
//
#include <hip/hip_runtime.h>

#define N_NODES 100000
#define N_EDGES 3200000
#define IN_DIM 500
#define HID 16
#define OUT_DIM 500

#define BSHIFT 9                 // 512 nodes per bucket
#define NBUCK 196                // ceil(100000/512); max bucket = 99999>>9 = 195
#define PLACE_CAP 24576          // staged csr ints per bucket (96 KB); mean 16384, sigma 128

// ================= degree / dis =================
__global__ void k_deg(const int* __restrict__ dst, int* __restrict__ cnt, int E) {
    int e = blockIdx.x * blockDim.x + threadIdx.x;
    if (e < E) atomicAdd(&cnt[dst[e]], 1);
}

__global__ void k_dis(const int* __restrict__ cnt, float* __restrict__ dis, int n) {
    int i = blockIdx.x * blockDim.x + threadIdx.x;
    if (i < n) dis[i] = rsqrtf((float)(cnt[i] + 1));  // +1 self-loop
}

// ================= CSR build: scan =================
__global__ __launch_bounds__(1024) void k_scanA(const int* __restrict__ cnt,
                                                int* __restrict__ rowptr,
                                                int* __restrict__ bsum) {
    __shared__ int sh[1024];
    int t = threadIdx.x;
    int i = blockIdx.x * 1024 + t;
    int v = (i < N_NODES) ? cnt[i] : 0;
    sh[t] = v;
    __syncthreads();
    for (int off = 1; off < 1024; off <<= 1) {
        int tmp = (t >= off) ? sh[t - off] : 0;
        __syncthreads();
        sh[t] += tmp;
        __syncthreads();
    }
    if (i < N_NODES) rowptr[i] = sh[t] - v;  // block-local exclusive
    if (t == 1023) bsum[blockIdx.x] = sh[1023];
}

__global__ __launch_bounds__(128) void k_scanB(int* __restrict__ bsum, int nb) {
    __shared__ int sh[128];
    int t = threadIdx.x;
    int v = (t < nb) ? bsum[t] : 0;
    sh[t] = v;
    __syncthreads();
    for (int off = 1; off < 128; off <<= 1) {
        int tmp = (t >= off) ? sh[t - off] : 0;
        __syncthreads();
        sh[t] += tmp;
        __syncthreads();
    }
    if (t < nb) bsum[t] = sh[t] - v;  // exclusive
}

__global__ void k_scanC(int* __restrict__ rowptr, const int* __restrict__ bsum) {
    int i = blockIdx.x * blockDim.x + threadIdx.x;
    if (i < N_NODES) rowptr[i] += bsum[i >> 10];
    if (i == 0) rowptr[N_NODES] = N_EDGES;
}

// ================= binned CSR fill =================
// Replaces the old k_fill (170us, WRITE_SIZE 197MB from 4B random scatter).
// Pass 1: bin edges into 196 coarse buckets (512 nodes each) as packed
// (src<<9)|dst_low entries; per-(block,bucket) runs are contiguous (~80B),
// bucket bases come exactly from rowptr[b<<9].
// Pass 2: one block per bucket stages its csr range in LDS (exact per-node
// position via LDS cursor atomics), then writes out fully coalesced.
__global__ void k_initcur(const int* __restrict__ rowptr, int* __restrict__ cur) {
    int b = blockIdx.x * blockDim.x + threadIdx.x;
    if (b < NBUCK) cur[b] = rowptr[b << BSHIFT];
}

__global__ __launch_bounds__(512) void k_bin(const int* __restrict__ src,
                                             const int* __restrict__ dst,
                                             int* __restrict__ cur,
                                             unsigned* __restrict__ ebin, int E) {
    __shared__ int hist[NBUCK];
    __shared__ int gbase[NBUCK];
    int t = threadIdx.x;
    for (int i = t; i < NBUCK; i += 512) hist[i] = 0;
    __syncthreads();
    int base = blockIdx.x * 8192;
    unsigned epack[16];  // (src<<9)|dst_low9
    unsigned lpack[16];  // (loc<<8)|bucket, 0xFFFFFFFF = invalid
#pragma unroll
    for (int q = 0; q < 16; ++q) {
        int e = base + q * 512 + t;
        unsigned ep = 0, lp = 0xFFFFFFFFu;
        if (e < E) {
            int s = src[e];
            int d = dst[e];
            int b = d >> BSHIFT;
            int loc = atomicAdd(&hist[b], 1);
            ep = ((unsigned)s << BSHIFT) | (unsigned)(d & 511);
            lp = ((unsigned)loc << 8) | (unsigned)b;
        }
        epack[q] = ep;
        lpack[q] = lp;
    }
    __syncthreads();
    for (int i = t; i < NBUCK; i += 512)
        gbase[i] = hist[i] ? atomicAdd(&cur[i], hist[i]) : 0;
    __syncthreads();
#pragma unroll
    for (int q = 0; q < 16; ++q) {
        if (lpack[q] != 0xFFFFFFFFu) {
            int b = (int)(lpack[q] & 255u);
            int loc = (int)(lpack[q] >> 8);
            ebin[gbase[b] + loc] = epack[q];
        }
    }
}

__global__ __launch_bounds__(1024) void k_place(const int* __restrict__ rowptr,
                                                const unsigned* __restrict__ ebin,
                                                int* __restrict__ csr,
                                                int* __restrict__ cnt) {
    __shared__ int stage[PLACE_CAP];  // 96 KB
    __shared__ int rloc[513];
    __shared__ int lcur[512];
    int b = blockIdx.x;
    int n0 = b << BSHIFT;
    int n1 = n0 + 512;
    if (n1 > N_NODES) n1 = N_NODES;
    int nn = n1 - n0;
    int t = threadIdx.x;
    int base = rowptr[n0];
    for (int i = t; i <= nn; i += 1024) rloc[i] = rowptr[n0 + i] - base;
    for (int i = t; i < nn; i += 1024) lcur[i] = 0;
    __syncthreads();
    int size = rloc[nn];
    if (size <= PLACE_CAP) {
        for (int i = t; i < size; i += 1024) {
            unsigned p = ebin[base + i];
            int dlow = (int)(p & 511u);
            int pos = atomicAdd(&lcur[dlow], 1);
            stage[rloc[dlow] + pos] = (int)(p >> BSHIFT);
        }
        __syncthreads();
        for (int i = t; i < size; i += 1024) csr[base + i] = stage[i];
    } else {
        // improbable overflow fallback: direct global scatter (cnt zeroed)
        for (int i = t; i < size; i += 1024) {
            unsigned p = ebin[base + i];
            int d = n0 + (int)(p & 511u);
            int pos = rowptr[d] + atomicAdd(&cnt[d], 1);
            csr[pos] = (int)(p >> BSHIFT);
        }
    }
}

// ================= hp[N,16] = dis * (x[N,500] @ W[500,16]) =================
// row-per-lane + scalar-pipe W + 2-stage software pipeline (verified R3)
__global__ __launch_bounds__(256) void k_mm1(const float* __restrict__ x,
                                             const float* __restrict__ W,
                                             const float* __restrict__ dis,
                                             float* __restrict__ hp) {
    int row = blockIdx.x * 256 + threadIdx.x;
    if (row >= N_NODES) return;
    const float4* xr = (const float4*)(x + (size_t)row * IN_DIM);
    float acc[HID];
#pragma unroll
    for (int j = 0; j < HID; ++j) acc[j] = 0.0f;

    float4 A[8], B[8];
#pragma unroll
    for (int m = 0; m < 8; ++m) A[m] = xr[m];

#define MM1_GROUP(buf, g)                                                 \
    {                                                                     \
        const float* Wg = W + (size_t)(g) * 32 * HID;                     \
        _Pragma("unroll") for (int m = 0; m < 8; ++m) {                   \
            float4 a = buf[m];                                            \
            _Pragma("unroll") for (int j = 0; j < HID; ++j) {             \
                acc[j] += a.x * Wg[(4 * m + 0) * HID + j]                 \
                        + a.y * Wg[(4 * m + 1) * HID + j]                 \
                        + a.z * Wg[(4 * m + 2) * HID + j]                 \
                        + a.w * Wg[(4 * m + 3) * HID + j];                \
            }                                                             \
        }                                                                 \
    }

    for (int gg = 0; gg < 7; ++gg) {
        int g0 = 2 * gg;
#pragma unroll
        for (int m = 0; m < 8; ++m) B[m] = xr[8 * (g0 + 1) + m];
        MM1_GROUP(A, g0);
#pragma unroll
        for (int m = 0; m < 8; ++m) A[m] = xr[8 * (g0 + 2) + m];
        MM1_GROUP(B, g0 + 1);
    }
    MM1_GROUP(A, 14);
#pragma unroll
    for (int m = 0; m < 5; ++m) {
        float4 a = xr[120 + m];
        const float* Wg = W + (size_t)(480 + 4 * m) * HID;
#pragma unroll
        for (int j = 0; j < HID; ++j) {
            acc[j] += a.x * Wg[j] + a.y * Wg[HID + j] +
                      a.z * Wg[2 * HID + j] + a.w * Wg[3 * HID + j];
        }
    }
#undef MM1_GROUP

    float di = dis[row];
    float4* hr = (float4*)(hp + (size_t)row * HID);
#pragma unroll
    for (int q = 0; q < 4; ++q)
        hr[q] = make_float4(di * acc[4 * q + 0], di * acc[4 * q + 1],
                            di * acc[4 * q + 2], di * acc[4 * q + 3]);
}

// ================= hp[N,16] = dis * (o[N,16] @ W[16,16]) =================
__global__ __launch_bounds__(256) void k_mm2(const float* __restrict__ o,
                                             const float* __restrict__ W,
                                             const float* __restrict__ dis,
                                             float* __restrict__ hp) {
    int row = blockIdx.x * 256 + threadIdx.x;
    if (row >= N_NODES) return;
    const float4* orow = (const float4*)(o + (size_t)row * HID);
    float av[HID];
#pragma unroll
    for (int q = 0; q < 4; ++q) {
        float4 a = orow[q];
        av[4 * q + 0] = a.x; av[4 * q + 1] = a.y;
        av[4 * q + 2] = a.z; av[4 * q + 3] = a.w;
    }
    float acc[HID];
#pragma unroll
    for (int j = 0; j < HID; ++j) acc[j] = 0.0f;
#pragma unroll
    for (int k = 0; k < HID; ++k) {
#pragma unroll
        for (int j = 0; j < HID; ++j) acc[j] += av[k] * W[k * HID + j];
    }
    float di = dis[row];
    float4* hr = (float4*)(hp + (size_t)row * HID);
#pragma unroll
    for (int q = 0; q < 4; ++q)
        hr[q] = make_float4(di * acc[4 * q + 0], di * acc[4 * q + 1],
                            di * acc[4 * q + 2], di * acc[4 * q + 3]);
}

// ================= hp = dis * o (elementwise, layer-3 pre-agg) =================
__global__ void k_scale(const float* __restrict__ o, const float* __restrict__ dis,
                        float* __restrict__ hp) {
    int t = blockIdx.x * blockDim.x + threadIdx.x;
    if (t < N_NODES * HID) hp[t] = dis[t >> 4] * o[t];
}

// ================= gather: o[d] = [relu](dis[d]*(sum hp[src] + hp[d]) [+ b]) ====
template <int RELU>
__global__ __launch_bounds__(256) void k_gather(const int* __restrict__ rowptr,
                                                const int* __restrict__ csr,
                                                const float* __restrict__ dis,
                                                const float* __restrict__ hp,
                                                const float* __restrict__ b,
                                                float* __restrict__ o) {
    int g = threadIdx.x >> 4;   // 16 node-groups per block
    int f = threadIdx.x & 15;   // feature lane
    int d = blockIdx.x * 16 + g;
    int start = rowptr[d];
    int end = rowptr[d + 1];
    float s = 0.0f;
    for (int e0 = start; e0 < end; e0 += 16) {
        int idx = e0 + f;
        int sid = (idx < end) ? csr[idx] : 0;
        int m = end - e0;
        if (m > 16) m = 16;
        for (int j = 0; j < m; ++j) {
            int sj = __shfl(sid, j, 16);  // uniform within the 16-lane group
            s += hp[(size_t)sj * HID + f];
        }
    }
    float di = dis[d];
    float v = di * (s + hp[(size_t)d * HID + f]);
    if (RELU) {
        v += b[f];
        v = v > 0.0f ? v : 0.0f;
    }
    o[(size_t)d * HID + f] = v;
}

// ================= out[N,500] = a[N,16] @ W[16,500] + b =================
__global__ __launch_bounds__(256) void k_mm3(const float* __restrict__ a,
                                             const float* __restrict__ W,
                                             const float* __restrict__ b,
                                             float* __restrict__ out) {
    __shared__ float Ws[HID * OUT_DIM];  // 32000 B
    __shared__ float bs[OUT_DIM];
    for (int t = threadIdx.x; t < HID * OUT_DIM; t += 256) Ws[t] = W[t];
    for (int t = threadIdx.x; t < OUT_DIM; t += 256) bs[t] = b[t];
    __syncthreads();
    int ct = threadIdx.x & 127;  // 0..127 (125 active)
    int rt = threadIdx.x >> 7;   // 0..1
    int r0 = blockIdx.x * 8 + rt * 4;
    float areg[4][16];
#pragma unroll
    for (int rr = 0; rr < 4; ++rr) {
        const float4* ap = (const float4*)(a + (size_t)(r0 + rr) * HID);
        float4 v0 = ap[0], v1 = ap[1], v2 = ap[2], v3 = ap[3];
        areg[rr][0] = v0.x;  areg[rr][1] = v0.y;  areg[rr][2] = v0.z;  areg[rr][3] = v0.w;
        areg[rr][4] = v1.x;  areg[rr][5] = v1.y;  areg[rr][6] = v1.z;  areg[rr][7] = v1.w;
        areg[rr][8] = v2.x;  areg[rr][9] = v2.y;  areg[rr][10] = v2.z; areg[rr][11] = v2.w;
        areg[rr][12] = v3.x; areg[rr][13] = v3.y; areg[rr][14] = v3.z; areg[rr][15] = v3.w;
    }
    if (ct >= 125) return;
    int j0 = ct * 4;
    float acc[4][4];
#pragma unroll
    for (int rr = 0; rr < 4; ++rr) {
        acc[rr][0] = bs[j0];
        acc[rr][1] = bs[j0 + 1];
        acc[rr][2] = bs[j0 + 2];
        acc[rr][3] = bs[j0 + 3];
    }
#pragma unroll
    for (int k = 0; k < HID; ++k) {
        float4 w = *(const float4*)&Ws[k * OUT_DIM + j0];
#pragma unroll
        for (int rr = 0; rr < 4; ++rr) {
            acc[rr][0] += areg[rr][k] * w.x;
            acc[rr][1] += areg[rr][k] * w.y;
            acc[rr][2] += areg[rr][k] * w.z;
            acc[rr][3] += areg[rr][k] * w.w;
        }
    }
#pragma unroll
    for (int rr = 0; rr < 4; ++rr) {
        float4 r = make_float4(acc[rr][0], acc[rr][1], acc[rr][2], acc[rr][3]);
        *(float4*)&out[(size_t)(r0 + rr) * OUT_DIM + j0] = r;
    }
}

extern "C" void kernel_launch(void* const* d_in, const int* in_sizes, int n_in,
                              void* d_out, int out_size, void* d_ws, size_t ws_size,
                              hipStream_t stream) {
    const float* x  = (const float*)d_in[0];
    const int* ei   = (const int*)d_in[1];
    const float* W1 = (const float*)d_in[2];
    const float* b1 = (const float*)d_in[3];
    const float* W2 = (const float*)d_in[4];
    const float* b2 = (const float*)d_in[5];
    const float* W3 = (const float*)d_in[6];
    const float* b3 = (const float*)d_in[7];
    float* out = (float*)d_out;

    const int* src = ei;
    const int* dst = ei + N_EDGES;

    // workspace layout (bytes) — total 26,805,760 (same as verified R3 layout)
    char* w = (char*)d_ws;
    float* dis      = (float*)(w);                 // 100352 f
    int*   cnt      = (int*)(w + 401408);          // 100000 i used (fallback cursor)
    int*   cur      = (int*)(w + 801408);          // 196 i (slack after cnt)
    int*   rowptr   = (int*)(w + 802816);          // 100608 i
    int*   bsum     = (int*)(w + 1205248);         // 128 i
    int*   csr      = (int*)(w + 1205760);         // 3.2M i
    float* hp       = (float*)(w + 14005760);      // 1.6M f
    float* o        = (float*)(w + 20405760);      // 1.6M f
    unsigned* ebin  = (unsigned*)(w + 14005760);   // 3.2M u32, aliases hp+o (dead then)

    const int B = 256;
    int gN   = (N_NODES + B - 1) / B;         // 391
    int gE   = (N_EDGES + B - 1) / B;
    int gNH  = (N_NODES * HID + B - 1) / B;   // 6250
    int gG   = N_NODES / 16;                  // 6250 (exact)
    int gMM3 = N_NODES / 8;                   // 12500 (exact)
    int gScanA = (N_NODES + 1023) / 1024;     // 98
    int gBin = (N_EDGES + 8191) / 8192;       // 391

    // ---- degree & dis ----
    hipMemsetAsync(cnt, 0, N_NODES * sizeof(int), stream);
    k_deg<<<gE, B, 0, stream>>>(dst, cnt, N_EDGES);
    k_dis<<<gN, B, 0, stream>>>(cnt, dis, N_NODES);

    // ---- CSR build ----
    k_scanA<<<gScanA, 1024, 0, stream>>>(cnt, rowptr, bsum);
    k_scanB<<<1, 128, 0, stream>>>(bsum, gScanA);
    k_scanC<<<gN, B, 0, stream>>>(rowptr, bsum);
    k_initcur<<<1, 256, 0, stream>>>(rowptr, cur);
    k_bin<<<gBin, 512, 0, stream>>>(src, dst, cur, ebin, N_EDGES);
    hipMemsetAsync(cnt, 0, N_NODES * sizeof(int), stream);  // fallback cursor
    k_place<<<NBUCK, 1024, 0, stream>>>(rowptr, ebin, csr, cnt);

    // ---- layer 1 ----
    k_mm1<<<gN, B, 0, stream>>>(x, W1, dis, hp);
    k_gather<1><<<gG, B, 0, stream>>>(rowptr, csr, dis, hp, b1, o);

    // ---- layer 2 ----
    k_mm2<<<gN, B, 0, stream>>>(o, W2, dis, hp);
    k_gather<1><<<gG, B, 0, stream>>>(rowptr, csr, dis, hp, b2, o);

    // ---- layer 3: aggregate at 16 dims, then W3 ----
    k_scale<<<gNH, B, 0, stream>>>(o, dis, hp);
    k_gather<0><<<gG, B, 0, stream>>>(rowptr, csr, dis, hp, b3, o);
    k_mm3<<<gMM3, B, 0, stream>>>(o, W3, b3, out);
}